// Round 8
// baseline (225.573 us; speedup 1.0000x reference)
//
#include <hip/hip_runtime.h>
#include <hip/hip_bf16.h>

// MSDeformAttn: B=2, LQ=LV=11109, D=256, NH=8, HD=32, NL=3, NP=4
// shapes: (92,92),(46,46),(23,23); starts: 0, 8464, 10580
#define LQn   11109
#define MTOT  22218   // B * LQ

typedef __attribute__((ext_vector_type(8))) short short8;
typedef __attribute__((ext_vector_type(4))) float f32x4;

__device__ __forceinline__ unsigned short f2bf(float f) {
  union { float f; unsigned int u; } v; v.f = f;
  unsigned int r = v.u + 0x7fffu + ((v.u >> 16) & 1u);  // RNE
  return (unsigned short)(r >> 16);
}

// pack 8 fp32 -> 8 bf16 (RNE, v_cvt_pk_bf16_f32 on gfx950)
__device__ __forceinline__ short8 pack8(float4 a, float4 b) {
  union { __hip_bfloat162 h[4]; short8 s; } u;
  u.h[0] = __float22bfloat162_rn(make_float2(a.x, a.y));
  u.h[1] = __float22bfloat162_rn(make_float2(a.z, a.w));
  u.h[2] = __float22bfloat162_rn(make_float2(b.x, b.y));
  u.h[3] = __float22bfloat162_rn(make_float2(b.z, b.w));
  return u.s;
}

// ---------------- weight prep: coalesced reads, scattered (posted) writes ----------
// grid 256 (k), block 320 (n). Wcat_t/bcat padded to 320 rows (288..319 = 0).
__global__ __launch_bounds__(320) void prep_weights2(
    const float* __restrict__ Wval, const float* __restrict__ Woff,
    const float* __restrict__ Wattn, const float* __restrict__ Wout,
    const float* __restrict__ boff, const float* __restrict__ battn,
    unsigned short* __restrict__ Wval_t, unsigned short* __restrict__ Wcat_t,
    unsigned short* __restrict__ Wout_t, float* __restrict__ bcat) {
  const int k = blockIdx.x;    // 0..255
  const int n = threadIdx.x;   // 0..319
  if (n < 256) {
    Wval_t[n * 256 + k] = f2bf(Wval[k * 256 + n]);
    Wout_t[n * 256 + k] = f2bf(Wout[k * 256 + n]);
  }
  float c = (n < 192) ? Woff[k * 192 + n] : (n < 288 ? Wattn[k * 96 + (n - 192)] : 0.f);
  Wcat_t[n * 256 + k] = f2bf(c);
  if (k == 0) bcat[n] = (n < 192) ? boff[n] : (n < 288 ? battn[n - 192] : 0.f);
}

// ---------------- GEMM1+2: 4 independent wave-tiles per 256-block ----------
// 3132 wave-tiles: id = bn*348 + bm; bn<4 -> value proj, bn>=4 -> logits proj.
// No LDS, no barriers; A fp32 converted in-register.
__global__ __launch_bounds__(256) void gemm12_tile4(
    const float* __restrict__ Aval, const float* __restrict__ Aq,
    const unsigned short* __restrict__ Bval, const unsigned short* __restrict__ Bcat,
    const float* __restrict__ bval, const float* __restrict__ bcat,
    unsigned short* __restrict__ value16,    // [b][h][pix][32] bf16
    float* __restrict__ logits) {            // (M,288) fp32
  const int id = blockIdx.x * 4 + (threadIdx.x >> 6);
  if (id >= 3132) return;
  int bn = id / 348;
  const int bm = id - bn * 348;
  const bool is2 = bn >= 4;
  if (is2) bn -= 4;
  const float* __restrict__ A = is2 ? Aq : Aval;
  const unsigned short* __restrict__ Bt = is2 ? Bcat : Bval;

  const int t = threadIdx.x & 63;
  const int quad = t >> 4, l16 = t & 15;

  const float* aptr[4];
#pragma unroll
  for (int i = 0; i < 4; i++) {
    int r = bm * 64 + i * 16 + l16;
    r = (r < MTOT) ? r : (MTOT - 1);
    aptr[i] = A + (size_t)r * 256 + quad * 8;
  }
  const unsigned short* bptr[4];
#pragma unroll
  for (int j = 0; j < 4; j++)
    bptr[j] = Bt + (size_t)(bn * 64 + j * 16 + l16) * 256 + quad * 8;

  f32x4 acc[4][4];
#pragma unroll
  for (int i = 0; i < 4; i++)
#pragma unroll
    for (int j = 0; j < 4; j++) acc[i][j] = (f32x4){0.f, 0.f, 0.f, 0.f};

#pragma unroll
  for (int kb = 0; kb < 8; kb++) {
    short8 af[4], bfr[4];
#pragma unroll
    for (int i = 0; i < 4; i++) {
      float4 a0 = *(const float4*)(aptr[i] + kb * 32);
      float4 a1 = *(const float4*)(aptr[i] + kb * 32 + 4);
      af[i] = pack8(a0, a1);
    }
#pragma unroll
    for (int j = 0; j < 4; j++)
      bfr[j] = *(const short8*)(bptr[j] + kb * 32);
#pragma unroll
    for (int i = 0; i < 4; i++)
#pragma unroll
      for (int j = 0; j < 4; j++)
        acc[i][j] = __builtin_amdgcn_mfma_f32_16x16x32_bf16(af[i], bfr[j], acc[i][j], 0, 0, 0);
  }

  // D: col = l16, row = quad*4 + r
  if (!is2) {
#pragma unroll
    for (int j = 0; j < 4; j++) {
      const int col = bn * 64 + j * 16 + l16;       // < 256
      const float bs = bval[col];
      const int h = col >> 5, cch = col & 31;
#pragma unroll
      for (int i = 0; i < 4; i++) {
        const int row0 = bm * 64 + i * 16 + quad * 4;
#pragma unroll
        for (int r = 0; r < 4; r++) {
          const int rg = row0 + r;
          if (rg >= MTOT) continue;
          const int b = (rg >= LQn) ? 1 : 0;
          const int p = rg - b * LQn;
          value16[((size_t)(b * 8 + h) * LQn + p) * 32 + cch] = f2bf(acc[i][j][r] + bs);
        }
      }
    }
  } else {
#pragma unroll
    for (int j = 0; j < 4; j++) {
      const int col = bn * 64 + j * 16 + l16;
      if (col >= 288) continue;
      const float bs = bcat[col];
#pragma unroll
      for (int i = 0; i < 4; i++) {
        const int row0 = bm * 64 + i * 16 + quad * 4;
#pragma unroll
        for (int r = 0; r < 4; r++) {
          const int rg = row0 + r;
          if (rg < MTOT) logits[(size_t)rg * 288 + col] = acc[i][j][r] + bs;
        }
      }
    }
  }
}

// ---------------- GEMM3 (out proj): 4 wave-tiles per 256-block, A bf16 ----------
__global__ __launch_bounds__(256) void gemm_out_tile4(
    const unsigned short* __restrict__ A,    // (M,256) bf16
    const unsigned short* __restrict__ Bt,   // (256,256) bf16 N-major
    const float* __restrict__ bias,
    float* __restrict__ C) {                 // (M,256) fp32
  const int id = blockIdx.x * 4 + (threadIdx.x >> 6);
  if (id >= 1392) return;
  const int bn = id / 348;
  const int bm = id - bn * 348;
  const int t = threadIdx.x & 63;
  const int quad = t >> 4, l16 = t & 15;

  const unsigned short* aptr[4];
#pragma unroll
  for (int i = 0; i < 4; i++) {
    int r = bm * 64 + i * 16 + l16;
    r = (r < MTOT) ? r : (MTOT - 1);
    aptr[i] = A + (size_t)r * 256 + quad * 8;
  }
  const unsigned short* bptr[4];
#pragma unroll
  for (int j = 0; j < 4; j++)
    bptr[j] = Bt + (size_t)(bn * 64 + j * 16 + l16) * 256 + quad * 8;

  f32x4 acc[4][4];
#pragma unroll
  for (int i = 0; i < 4; i++)
#pragma unroll
    for (int j = 0; j < 4; j++) acc[i][j] = (f32x4){0.f, 0.f, 0.f, 0.f};

#pragma unroll
  for (int kb = 0; kb < 8; kb++) {
    short8 af[4], bfr[4];
#pragma unroll
    for (int i = 0; i < 4; i++) af[i] = *(const short8*)(aptr[i] + kb * 32);
#pragma unroll
    for (int j = 0; j < 4; j++) bfr[j] = *(const short8*)(bptr[j] + kb * 32);
#pragma unroll
    for (int i = 0; i < 4; i++)
#pragma unroll
      for (int j = 0; j < 4; j++)
        acc[i][j] = __builtin_amdgcn_mfma_f32_16x16x32_bf16(af[i], bfr[j], acc[i][j], 0, 0, 0);
  }

#pragma unroll
  for (int j = 0; j < 4; j++) {
    const int col = bn * 64 + j * 16 + l16;
    const float bs = bias[col];
#pragma unroll
    for (int i = 0; i < 4; i++) {
      const int row0 = bm * 64 + i * 16 + quad * 4;
#pragma unroll
      for (int r = 0; r < 4; r++) {
        const int rg = row0 + r;
        if (rg < MTOT) C[(size_t)rg * 256 + col] = acc[i][j][r] + bs;
      }
    }
  }
}

// ---------------- sampling + softmax + weighted sum, v5 (unchanged) ----------------
__global__ __launch_bounds__(256) void msda_sample5(
    const unsigned short* __restrict__ value16,  // [b][h][pix][32] bf16
    const float* __restrict__ logits,            // (M,288)
    const float* __restrict__ refp,              // (M,3,2) (y,x)
    unsigned short* __restrict__ sampled) {      // (M,256) bf16
  __shared__ float          tw[8][96][4];
  __shared__ unsigned short ti[8][96][4];
  __shared__ float hmx[8][8], hrd[8][8];
  __shared__ float rfs[8][6];

  const int t = threadIdx.x;
  const int qbase = blockIdx.x * 8;

  if (t < 48) {
    int q = t / 6;
    if (qbase + q < MTOT) rfs[q][t - q * 6] = refp[(size_t)qbase * 6 + t];
  }
  if (t >= 64 && t < 128) {
    int tt = t - 64;
    int q = tt >> 3, h = tt & 7;
    int bq = qbase + q;
    if (bq < MTOT) {
      const float* lrow = logits + (size_t)bq * 288 + 192 + h * 12;
      float mx = -1e30f;
#pragma unroll
      for (int i = 0; i < 12; i++) mx = fmaxf(mx, lrow[i]);
      float den = 0.f;
#pragma unroll
      for (int i = 0; i < 12; i++) den += __expf(lrow[i] - mx);
      hmx[q][h] = mx;
      hrd[q][h] = 1.0f / den;
    }
  }
  __syncthreads();

  {
    const int Hs[3] = {92, 46, 23};
    const int Ss[3] = {0, 8464, 10580};
#pragma unroll
    for (int r = 0; r < 3; r++) {
      const int task = t + r * 256;
      const int q = task / 96, s = task - q * 96;   // s = slot = pl*8 + h
      const int bq = qbase + q;
      if (bq < MTOT) {
        const int h = s & 7, pl = s >> 3;
        const int l = pl >> 2;
        const int H = Hs[l], W = Hs[l], S = Ss[l];
        const int ob = h * 12 + pl;
        const float* lrow = logits + (size_t)bq * 288;
        const float aw = __expf(lrow[192 + ob] - hmx[q][h]) * hrd[q][h];
        const float offy = lrow[2 * ob], offx = lrow[2 * ob + 1];
        const float x = rfs[q][l * 2 + 1] * W + offx - 0.5f;
        const float y = rfs[q][l * 2 + 0] * H + offy - 0.5f;
        const float xf = floorf(x), yf = floorf(y);
        const int x0 = (int)xf, y0 = (int)yf;
        const float lx = x - xf, ly = y - yf;
        const bool xv0 = (x0 >= 0) & (x0 < W), xv1 = (x0 + 1 >= 0) & (x0 + 1 < W);
        const bool yv0 = (y0 >= 0) & (y0 < H), yv1 = (y0 + 1 >= 0) & (y0 + 1 < H);
        const int xc0 = min(max(x0, 0), W - 1), xc1 = min(max(x0 + 1, 0), W - 1);
        const int yc0 = min(max(y0, 0), H - 1), yc1 = min(max(y0 + 1, 0), H - 1);
        ti[q][s][0] = (unsigned short)(S + yc0 * W + xc0);
        ti[q][s][1] = (unsigned short)(S + yc0 * W + xc1);
        ti[q][s][2] = (unsigned short)(S + yc1 * W + xc0);
        ti[q][s][3] = (unsigned short)(S + yc1 * W + xc1);
        tw[q][s][0] = (yv0 & xv0) ? aw * (1.f - ly) * (1.f - lx) : 0.f;
        tw[q][s][1] = (yv0 & xv1) ? aw * (1.f - ly) * lx : 0.f;
        tw[q][s][2] = (yv1 & xv0) ? aw * ly * (1.f - lx) : 0.f;
        tw[q][s][3] = (yv1 & xv1) ? aw * ly * lx : 0.f;
      }
    }
  }
  __syncthreads();

  {
    const int w = t >> 6, lane = t & 63;
    const int q = w * 2 + (lane >> 5);
    const int h = (lane >> 2) & 7, cg = lane & 3;
    const int bq = qbase + q;
    const bool qv = bq < MTOT;
    const int bqc = qv ? bq : 0;
    const char* __restrict__ vb =
        (const char*)value16 + (size_t)(bqc / LQn) * ((size_t)LQn * 512);
    const unsigned laneoff = (unsigned)h * (LQn * 64u) + (unsigned)cg * 16u;

    float a0 = 0.f, a1 = 0.f, a2 = 0.f, a3 = 0.f;
    float a4 = 0.f, a5 = 0.f, a6 = 0.f, a7 = 0.f;
#pragma unroll
    for (int p = 0; p < 12; p++) {
      const int slot = p * 8 + h;
      const ushort4 tiv = *(const ushort4*)(&ti[q][slot][0]);
      const f32x4 wv = *(const f32x4*)(&tw[q][slot][0]);
#pragma unroll
      for (int k = 0; k < 4; k++) {
        const unsigned pix =
            (k == 0) ? tiv.x : (k == 1) ? tiv.y : (k == 2) ? tiv.z : tiv.w;
        const float wgt = wv[k];
        const uint4 u = *(const uint4*)(vb + ((pix << 6) + laneoff));
        a0 += wgt * __uint_as_float(u.x << 16);
        a1 += wgt * __uint_as_float(u.x & 0xffff0000u);
        a2 += wgt * __uint_as_float(u.y << 16);
        a3 += wgt * __uint_as_float(u.y & 0xffff0000u);
        a4 += wgt * __uint_as_float(u.z << 16);
        a5 += wgt * __uint_as_float(u.z & 0xffff0000u);
        a6 += wgt * __uint_as_float(u.w << 16);
        a7 += wgt * __uint_as_float(u.w & 0xffff0000u);
      }
    }
    if (qv) {
      uint4 o;
      o.x = (unsigned)f2bf(a0) | ((unsigned)f2bf(a1) << 16);
      o.y = (unsigned)f2bf(a2) | ((unsigned)f2bf(a3) << 16);
      o.z = (unsigned)f2bf(a4) | ((unsigned)f2bf(a5) << 16);
      o.w = (unsigned)f2bf(a6) | ((unsigned)f2bf(a7) << 16);
      *(uint4*)(sampled + (size_t)bq * 256 + h * 32 + cg * 8) = o;
    }
  }
}

// ---------------- host launch ----------------
extern "C" void kernel_launch(void* const* d_in, const int* in_sizes, int n_in,
                              void* d_out, int out_size, void* d_ws, size_t ws_size,
                              hipStream_t stream) {
  const float* query      = (const float*)d_in[0];
  const float* refp       = (const float*)d_in[1];
  const float* value_flat = (const float*)d_in[2];
  const float* W_val      = (const float*)d_in[3];
  const float* b_val      = (const float*)d_in[4];
  const float* W_off      = (const float*)d_in[5];
  const float* b_off      = (const float*)d_in[6];
  const float* W_attn     = (const float*)d_in[7];
  const float* b_attn     = (const float*)d_in[8];
  const float* W_out      = (const float*)d_in[9];
  const float* b_out      = (const float*)d_in[10];

  char* w = (char*)d_ws;
  size_t o = 0;
  auto carve = [&](size_t bytes) -> void* {
    void* p = (void*)(w + o);
    o += (bytes + 255) & ~(size_t)255;
    return p;
  };
  unsigned short* Wval_t  = (unsigned short*)carve(256 * 256 * 2);
  unsigned short* Wcat_t  = (unsigned short*)carve(320 * 256 * 2);
  unsigned short* Wout_t  = (unsigned short*)carve(256 * 256 * 2);
  float*          bcat    = (float*)carve(320 * 4);
  unsigned short* value16 = (unsigned short*)carve((size_t)MTOT * 256 * 2);
  float*          logits  = (float*)carve((size_t)MTOT * 288 * 4);
  unsigned short* samp_bf = (unsigned short*)carve((size_t)MTOT * 256 * 2);

  prep_weights2<<<256, 320, 0, stream>>>(W_val, W_off, W_attn, W_out, b_off, b_attn,
                                         Wval_t, Wcat_t, Wout_t, bcat);

  gemm12_tile4<<<783, 256, 0, stream>>>(value_flat, query, Wval_t, Wcat_t,
                                        b_val, bcat, value16, logits);

  const int sgrid = (MTOT + 7) / 8;              // 2778
  msda_sample5<<<sgrid, 256, 0, stream>>>(value16, logits, refp, samp_bf);

  gemm_out_tile4<<<348, 256, 0, stream>>>(samp_bf, Wout_t, b_out, (float*)d_out);
}

// Round 9
// 214.987 us; speedup vs baseline: 1.0492x; 1.0492x over previous
//
#include <hip/hip_runtime.h>

// MSDeformAttn: B=2, LQ=LV=11109, D=256, NH=8, HD=32, NL=3, NP=4
// shapes: (92,92),(46,46),(23,23); starts: 0, 8464, 10580
#define LQn   11109
#define MTOT  22218   // B * LQ

typedef __attribute__((ext_vector_type(8))) short short8;
typedef __attribute__((ext_vector_type(4))) float f32x4;

__device__ __forceinline__ unsigned short f2bf(float f) {
  union { float f; unsigned int u; } v; v.f = f;
  unsigned int r = v.u + 0x7fffu + ((v.u >> 16) & 1u);  // RNE
  return (unsigned short)(r >> 16);
}

// ---------------- weight prep: coalesced reads, scattered writes ----------
// grid 256 (k), block 320 (n).
__global__ __launch_bounds__(320) void prep_weights2(
    const float* __restrict__ Wval, const float* __restrict__ Woff,
    const float* __restrict__ Wattn, const float* __restrict__ Wout,
    const float* __restrict__ boff, const float* __restrict__ battn,
    unsigned short* __restrict__ Wval_t, unsigned short* __restrict__ Wcat_t,
    unsigned short* __restrict__ Wout_t, float* __restrict__ bcat) {
  const int k = blockIdx.x;    // 0..255
  const int n = threadIdx.x;   // 0..319
  if (n < 256) {
    Wval_t[n * 256 + k] = f2bf(Wval[k * 256 + n]);
    Wout_t[n * 256 + k] = f2bf(Wout[k * 256 + n]);
  }
  if (n < 288) {
    float c = (n < 192) ? Woff[k * 192 + n] : Wattn[k * 96 + (n - 192)];
    Wcat_t[n * 256 + k] = f2bf(c);
    if (k == 0) bcat[n] = (n < 192) ? boff[n] : battn[n - 192];
  }
}

// ---------------- fused GEMM1+GEMM2 (round-5 proven version) ----------------
// grid = (348, 9): bn<4 -> value proj (N=256, bf16 head-major out)
//                  bn>=4 -> logits proj (N=288, fp32 out)
__global__ __launch_bounds__(256) void gemm_fused12(
    const float* __restrict__ Aval,           // (M,256) fp32
    const float* __restrict__ Aq,             // (M,256) fp32
    const unsigned short* __restrict__ Bval,  // (256,256) bf16 N-major
    const unsigned short* __restrict__ Bcat,  // (288,256) bf16 N-major
    const float* __restrict__ bval, const float* __restrict__ bcat,
    unsigned short* __restrict__ value16,     // [b][h][pix][32] bf16
    float* __restrict__ logits) {             // (M,288) fp32
  __shared__ unsigned short As[64][40];
  __shared__ unsigned short Bs[64][40];

  const int bm = blockIdx.x;
  int bn = blockIdx.y;
  const bool is2 = bn >= 4;
  if (is2) bn -= 4;
  const float* __restrict__ A = is2 ? Aq : Aval;
  const unsigned short* __restrict__ Bt = is2 ? Bcat : Bval;
  const float* __restrict__ bias = is2 ? bcat : bval;
  const int N = is2 ? 288 : 256;

  const int t = threadIdx.x;
  const int wave = t >> 6, lane = t & 63;
  const int wm = wave >> 1, wn = wave & 1;
  const int quad = lane >> 4, l16 = lane & 15;

  const int ldr = t >> 2;
  const int ldk = (t & 3) * 8;
  const int arow = bm * 64 + ldr;
  const int brow = bn * 64 + ldr;

  f32x4 acc[2][2];
  for (int i = 0; i < 2; i++)
    for (int j = 0; j < 2; j++) acc[i][j] = (f32x4){0.f, 0.f, 0.f, 0.f};

  for (int kb = 0; kb < 8; kb++) {
    const int k0 = kb * 32;
    float4 a0 = {0.f, 0.f, 0.f, 0.f}, a1 = a0;
    uint4 bv = {0u, 0u, 0u, 0u};
    if (arow < MTOT) {
      a0 = *(const float4*)(A + (size_t)arow * 256 + k0 + ldk);
      a1 = *(const float4*)(A + (size_t)arow * 256 + k0 + ldk + 4);
    }
    if (brow < N) bv = *(const uint4*)(Bt + (size_t)brow * 256 + k0 + ldk);
    ushort4 lo, hi;
    lo.x = f2bf(a0.x); lo.y = f2bf(a0.y); lo.z = f2bf(a0.z); lo.w = f2bf(a0.w);
    hi.x = f2bf(a1.x); hi.y = f2bf(a1.y); hi.z = f2bf(a1.z); hi.w = f2bf(a1.w);
    __syncthreads();
    *(ushort4*)(&As[ldr][ldk]) = lo;
    *(ushort4*)(&As[ldr][ldk + 4]) = hi;
    *(uint4*)(&Bs[ldr][ldk]) = bv;
    __syncthreads();
    short8 af[2], bfr[2];
    for (int i = 0; i < 2; i++)
      af[i] = *(const short8*)(&As[wm * 32 + i * 16 + l16][quad * 8]);
    for (int j = 0; j < 2; j++)
      bfr[j] = *(const short8*)(&Bs[wn * 32 + j * 16 + l16][quad * 8]);
    for (int i = 0; i < 2; i++)
      for (int j = 0; j < 2; j++)
        acc[i][j] = __builtin_amdgcn_mfma_f32_16x16x32_bf16(af[i], bfr[j], acc[i][j], 0, 0, 0);
  }

  for (int i = 0; i < 2; i++)
    for (int j = 0; j < 2; j++) {
      int colg = bn * 64 + wn * 32 + j * 16 + l16;
      if (colg >= N) continue;
      float bsv = bias[colg];
      int row0 = bm * 64 + wm * 32 + i * 16 + quad * 4;
      for (int r = 0; r < 4; r++) {
        int rg = row0 + r;
        if (rg >= MTOT) continue;
        float v = acc[i][j][r] + bsv;
        if (is2) {
          logits[(size_t)rg * 288 + colg] = v;
        } else {
          int b = (rg >= LQn) ? 1 : 0;
          int p = rg - b * LQn;
          value16[((size_t)(b * 8 + (colg >> 5)) * LQn + p) * 32 + (colg & 31)] = f2bf(v);
        }
      }
    }
}

// ---------------- sampling + softmax + weighted sum + OUT-PROJ, v6 ----------------
// v5 sampler (8 queries/block) + fused out-projection:
// Phase C writes sampled rows to LDS sm[8][256]; Phase D: each wave does a
// 16x64x256 MFMA GEMM (rows 8..15 garbage, not stored) vs L2-resident Wout_t,
// writing fp32 d_out directly. Eliminates gemm_a16 dispatch + 23MB round-trip.
__global__ __launch_bounds__(256) void msda_sample6(
    const unsigned short* __restrict__ value16,  // [b][h][pix][32] bf16
    const float* __restrict__ logits,            // (M,288)
    const float* __restrict__ refp,              // (M,3,2) (y,x)
    const unsigned short* __restrict__ Wout_t,   // (256,256) bf16 N-major
    const float* __restrict__ bout,              // (256) fp32
    float* __restrict__ C) {                     // (M,256) fp32 out
  __shared__ float          tw[8][96][4];   // 12.3 KB
  __shared__ unsigned short ti[8][96][4];   // 6.1 KB
  __shared__ float hmx[8][8], hrd[8][8];
  __shared__ float rfs[8][6];
  __shared__ unsigned short sm[8][256];     // 4 KB sampled rows

  const int t = threadIdx.x;
  const int qbase = blockIdx.x * 8;

  if (t < 48) {
    int q = t / 6;
    if (qbase + q < MTOT) rfs[q][t - q * 6] = refp[(size_t)qbase * 6 + t];
  }
  if (t >= 64 && t < 128) {
    int tt = t - 64;
    int q = tt >> 3, h = tt & 7;
    int bq = qbase + q;
    if (bq < MTOT) {
      const float* lrow = logits + (size_t)bq * 288 + 192 + h * 12;
      float mx = -1e30f;
#pragma unroll
      for (int i = 0; i < 12; i++) mx = fmaxf(mx, lrow[i]);
      float den = 0.f;
#pragma unroll
      for (int i = 0; i < 12; i++) den += __expf(lrow[i] - mx);
      hmx[q][h] = mx;
      hrd[q][h] = 1.0f / den;
    }
  }
  __syncthreads();

  // Phase B: build tables, task id == (q, slot), conflict-free
  {
    const int Hs[3] = {92, 46, 23};
    const int Ss[3] = {0, 8464, 10580};
#pragma unroll
    for (int r = 0; r < 3; r++) {
      const int task = t + r * 256;
      const int q = task / 96, s = task - q * 96;   // s = slot = pl*8 + h
      const int bq = qbase + q;
      if (bq < MTOT) {
        const int h = s & 7, pl = s >> 3;
        const int l = pl >> 2;
        const int H = Hs[l], W = Hs[l], S = Ss[l];
        const int ob = h * 12 + pl;
        const float* lrow = logits + (size_t)bq * 288;
        const float aw = __expf(lrow[192 + ob] - hmx[q][h]) * hrd[q][h];
        const float offy = lrow[2 * ob], offx = lrow[2 * ob + 1];
        const float x = rfs[q][l * 2 + 1] * W + offx - 0.5f;
        const float y = rfs[q][l * 2 + 0] * H + offy - 0.5f;
        const float xf = floorf(x), yf = floorf(y);
        const int x0 = (int)xf, y0 = (int)yf;
        const float lx = x - xf, ly = y - yf;
        const bool xv0 = (x0 >= 0) & (x0 < W), xv1 = (x0 + 1 >= 0) & (x0 + 1 < W);
        const bool yv0 = (y0 >= 0) & (y0 < H), yv1 = (y0 + 1 >= 0) & (y0 + 1 < H);
        const int xc0 = min(max(x0, 0), W - 1), xc1 = min(max(x0 + 1, 0), W - 1);
        const int yc0 = min(max(y0, 0), H - 1), yc1 = min(max(y0 + 1, 0), H - 1);
        ti[q][s][0] = (unsigned short)(S + yc0 * W + xc0);
        ti[q][s][1] = (unsigned short)(S + yc0 * W + xc1);
        ti[q][s][2] = (unsigned short)(S + yc1 * W + xc0);
        ti[q][s][3] = (unsigned short)(S + yc1 * W + xc1);
        tw[q][s][0] = (yv0 & xv0) ? aw * (1.f - ly) * (1.f - lx) : 0.f;
        tw[q][s][1] = (yv0 & xv1) ? aw * (1.f - ly) * lx : 0.f;
        tw[q][s][2] = (yv1 & xv0) ? aw * ly * (1.f - lx) : 0.f;
        tw[q][s][3] = (yv1 & xv1) ? aw * ly * lx : 0.f;
      }
    }
  }
  __syncthreads();

  // Phase C: gather + weighted sum -> LDS sm
  {
    const int w = t >> 6, lane = t & 63;
    const int q = w * 2 + (lane >> 5);
    const int h = (lane >> 2) & 7, cg = lane & 3;
    const int bq = qbase + q;
    const int bqc = (bq < MTOT) ? bq : 0;
    const char* __restrict__ vb =
        (const char*)value16 + (size_t)(bqc / LQn) * ((size_t)LQn * 512);
    const unsigned laneoff = (unsigned)h * (LQn * 64u) + (unsigned)cg * 16u;

    float a0 = 0.f, a1 = 0.f, a2 = 0.f, a3 = 0.f;
    float a4 = 0.f, a5 = 0.f, a6 = 0.f, a7 = 0.f;
#pragma unroll
    for (int p = 0; p < 12; p++) {
      const int slot = p * 8 + h;
      const ushort4 tiv = *(const ushort4*)(&ti[q][slot][0]);
      const f32x4 wv = *(const f32x4*)(&tw[q][slot][0]);
#pragma unroll
      for (int k = 0; k < 4; k++) {
        const unsigned pix =
            (k == 0) ? tiv.x : (k == 1) ? tiv.y : (k == 2) ? tiv.z : tiv.w;
        const float wgt = wv[k];
        const uint4 u = *(const uint4*)(vb + ((pix << 6) + laneoff));
        a0 += wgt * __uint_as_float(u.x << 16);
        a1 += wgt * __uint_as_float(u.x & 0xffff0000u);
        a2 += wgt * __uint_as_float(u.y << 16);
        a3 += wgt * __uint_as_float(u.y & 0xffff0000u);
        a4 += wgt * __uint_as_float(u.z << 16);
        a5 += wgt * __uint_as_float(u.z & 0xffff0000u);
        a6 += wgt * __uint_as_float(u.w << 16);
        a7 += wgt * __uint_as_float(u.w & 0xffff0000u);
      }
    }
    uint4 o;
    o.x = (unsigned)f2bf(a0) | ((unsigned)f2bf(a1) << 16);
    o.y = (unsigned)f2bf(a2) | ((unsigned)f2bf(a3) << 16);
    o.z = (unsigned)f2bf(a4) | ((unsigned)f2bf(a5) << 16);
    o.w = (unsigned)f2bf(a6) | ((unsigned)f2bf(a7) << 16);
    *(uint4*)(&sm[q][h * 32 + cg * 8]) = o;  // LDS, not global
  }
  __syncthreads();

  // Phase D: out-proj mini-GEMM. Wave w -> cols [w*64, w*64+64).
  // A rows: sm[l16&7] (rows 8..15 of the MFMA tile are duplicates; their C
  // rows are simply not stored -- MFMA rows are independent).
  {
    const int w = t >> 6, lane = t & 63;
    const int quad = lane >> 4, l16 = lane & 15;
    f32x4 acc[4];
#pragma unroll
    for (int j = 0; j < 4; j++) acc[j] = (f32x4){0.f, 0.f, 0.f, 0.f};

#pragma unroll
    for (int kb = 0; kb < 8; kb++) {
      const short8 af = *(const short8*)(&sm[l16 & 7][kb * 32 + quad * 8]);
#pragma unroll
      for (int j = 0; j < 4; j++) {
        const int col = w * 64 + j * 16 + l16;
        const short8 bf = *(const short8*)(Wout_t + (size_t)col * 256 + kb * 32 + quad * 8);
        acc[j] = __builtin_amdgcn_mfma_f32_16x16x32_bf16(af, bf, acc[j], 0, 0, 0);
      }
    }
#pragma unroll
    for (int j = 0; j < 4; j++) {
      const int col = w * 64 + j * 16 + l16;
      const float bs = bout[col];
#pragma unroll
      for (int r = 0; r < 4; r++) {
        const int rg = quad * 4 + r;     // MFMA tile row
        if (rg < 8) {
          const int gq = qbase + rg;
          if (gq < MTOT) C[(size_t)gq * 256 + col] = acc[j][r] + bs;
        }
      }
    }
  }
}

// ---------------- host launch ----------------
extern "C" void kernel_launch(void* const* d_in, const int* in_sizes, int n_in,
                              void* d_out, int out_size, void* d_ws, size_t ws_size,
                              hipStream_t stream) {
  const float* query      = (const float*)d_in[0];
  const float* refp       = (const float*)d_in[1];
  const float* value_flat = (const float*)d_in[2];
  const float* W_val      = (const float*)d_in[3];
  const float* b_val      = (const float*)d_in[4];
  const float* W_off      = (const float*)d_in[5];
  const float* b_off      = (const float*)d_in[6];
  const float* W_attn     = (const float*)d_in[7];
  const float* b_attn     = (const float*)d_in[8];
  const float* W_out      = (const float*)d_in[9];
  const float* b_out      = (const float*)d_in[10];

  char* w = (char*)d_ws;
  size_t o = 0;
  auto carve = [&](size_t bytes) -> void* {
    void* p = (void*)(w + o);
    o += (bytes + 255) & ~(size_t)255;
    return p;
  };
  unsigned short* Wval_t  = (unsigned short*)carve(256 * 256 * 2);
  unsigned short* Wcat_t  = (unsigned short*)carve(288 * 256 * 2);
  unsigned short* Wout_t  = (unsigned short*)carve(256 * 256 * 2);
  float*          bcat    = (float*)carve(288 * 4);
  unsigned short* value16 = (unsigned short*)carve((size_t)MTOT * 256 * 2);
  float*          logits  = (float*)carve((size_t)MTOT * 288 * 4);

  prep_weights2<<<256, 320, 0, stream>>>(W_val, W_off, W_attn, W_out, b_off, b_attn,
                                         Wval_t, Wcat_t, Wout_t, bcat);

  const int mg = (MTOT + 63) / 64;               // 348
  dim3 g12(mg, 9);                               // 4 value-proj tiles + 5 logits tiles
  gemm_fused12<<<g12, 256, 0, stream>>>(value_flat, query, Wval_t, Wcat_t,
                                        b_val, bcat, value16, logits);

  const int sgrid = (MTOT + 7) / 8;              // 2778
  msda_sample6<<<sgrid, 256, 0, stream>>>(value16, logits, refp,
                                          Wout_t, b_out, (float*)d_out);
}

// Round 10
// 199.011 us; speedup vs baseline: 1.1335x; 1.0803x over previous
//
#include <hip/hip_runtime.h>

// MSDeformAttn: B=2, LQ=LV=11109, D=256, NH=8, HD=32, NL=3, NP=4
// shapes: (92,92),(46,46),(23,23); starts: 0, 8464, 10580
#define LQn   11109
#define MTOT  22218   // B * LQ

typedef __attribute__((ext_vector_type(8))) short short8;
typedef __attribute__((ext_vector_type(4))) float f32x4;

__device__ __forceinline__ unsigned short f2bf(float f) {
  union { float f; unsigned int u; } v; v.f = f;
  unsigned int r = v.u + 0x7fffu + ((v.u >> 16) & 1u);  // RNE
  return (unsigned short)(r >> 16);
}

// ---------------- weight prep: coalesced reads, scattered writes ----------
// grid 256 (k), block 320 (n).
__global__ __launch_bounds__(320) void prep_weights2(
    const float* __restrict__ Wval, const float* __restrict__ Woff,
    const float* __restrict__ Wattn, const float* __restrict__ Wout,
    const float* __restrict__ boff, const float* __restrict__ battn,
    unsigned short* __restrict__ Wval_t, unsigned short* __restrict__ Wcat_t,
    unsigned short* __restrict__ Wout_t, float* __restrict__ bcat) {
  const int k = blockIdx.x;    // 0..255
  const int n = threadIdx.x;   // 0..319
  if (n < 256) {
    Wval_t[n * 256 + k] = f2bf(Wval[k * 256 + n]);
    Wout_t[n * 256 + k] = f2bf(Wout[k * 256 + n]);
  }
  if (n < 288) {
    float c = (n < 192) ? Woff[k * 192 + n] : Wattn[k * 96 + (n - 192)];
    Wcat_t[n * 256 + k] = f2bf(c);
    if (k == 0) bcat[n] = (n < 192) ? boff[n] : battn[n - 192];
  }
}

// ---------------- fused GEMM1+GEMM2 (round-5 proven version) ----------------
// grid = (348, 9): bn<4 -> value proj (N=256, bf16 head-major out)
//                  bn>=4 -> logits proj (N=288, fp32 out)
__global__ __launch_bounds__(256) void gemm_fused12(
    const float* __restrict__ Aval,           // (M,256) fp32
    const float* __restrict__ Aq,             // (M,256) fp32
    const unsigned short* __restrict__ Bval,  // (256,256) bf16 N-major
    const unsigned short* __restrict__ Bcat,  // (288,256) bf16 N-major
    const float* __restrict__ bval, const float* __restrict__ bcat,
    unsigned short* __restrict__ value16,     // [b][h][pix][32] bf16
    float* __restrict__ logits) {             // (M,288) fp32
  __shared__ unsigned short As[64][40];
  __shared__ unsigned short Bs[64][40];

  const int bm = blockIdx.x;
  int bn = blockIdx.y;
  const bool is2 = bn >= 4;
  if (is2) bn -= 4;
  const float* __restrict__ A = is2 ? Aq : Aval;
  const unsigned short* __restrict__ Bt = is2 ? Bcat : Bval;
  const float* __restrict__ bias = is2 ? bcat : bval;
  const int N = is2 ? 288 : 256;

  const int t = threadIdx.x;
  const int wave = t >> 6, lane = t & 63;
  const int wm = wave >> 1, wn = wave & 1;
  const int quad = lane >> 4, l16 = lane & 15;

  const int ldr = t >> 2;
  const int ldk = (t & 3) * 8;
  const int arow = bm * 64 + ldr;
  const int brow = bn * 64 + ldr;

  f32x4 acc[2][2];
  for (int i = 0; i < 2; i++)
    for (int j = 0; j < 2; j++) acc[i][j] = (f32x4){0.f, 0.f, 0.f, 0.f};

  for (int kb = 0; kb < 8; kb++) {
    const int k0 = kb * 32;
    float4 a0 = {0.f, 0.f, 0.f, 0.f}, a1 = a0;
    uint4 bv = {0u, 0u, 0u, 0u};
    if (arow < MTOT) {
      a0 = *(const float4*)(A + (size_t)arow * 256 + k0 + ldk);
      a1 = *(const float4*)(A + (size_t)arow * 256 + k0 + ldk + 4);
    }
    if (brow < N) bv = *(const uint4*)(Bt + (size_t)brow * 256 + k0 + ldk);
    ushort4 lo, hi;
    lo.x = f2bf(a0.x); lo.y = f2bf(a0.y); lo.z = f2bf(a0.z); lo.w = f2bf(a0.w);
    hi.x = f2bf(a1.x); hi.y = f2bf(a1.y); hi.z = f2bf(a1.z); hi.w = f2bf(a1.w);
    __syncthreads();
    *(ushort4*)(&As[ldr][ldk]) = lo;
    *(ushort4*)(&As[ldr][ldk + 4]) = hi;
    *(uint4*)(&Bs[ldr][ldk]) = bv;
    __syncthreads();
    short8 af[2], bfr[2];
    for (int i = 0; i < 2; i++)
      af[i] = *(const short8*)(&As[wm * 32 + i * 16 + l16][quad * 8]);
    for (int j = 0; j < 2; j++)
      bfr[j] = *(const short8*)(&Bs[wn * 32 + j * 16 + l16][quad * 8]);
    for (int i = 0; i < 2; i++)
      for (int j = 0; j < 2; j++)
        acc[i][j] = __builtin_amdgcn_mfma_f32_16x16x32_bf16(af[i], bfr[j], acc[i][j], 0, 0, 0);
  }

  for (int i = 0; i < 2; i++)
    for (int j = 0; j < 2; j++) {
      int colg = bn * 64 + wn * 32 + j * 16 + l16;
      if (colg >= N) continue;
      float bsv = bias[colg];
      int row0 = bm * 64 + wm * 32 + i * 16 + quad * 4;
      for (int r = 0; r < 4; r++) {
        int rg = row0 + r;
        if (rg >= MTOT) continue;
        float v = acc[i][j][r] + bsv;
        if (is2) {
          logits[(size_t)rg * 288 + colg] = v;
        } else {
          int b = (rg >= LQn) ? 1 : 0;
          int p = rg - b * LQn;
          value16[((size_t)(b * 8 + (colg >> 5)) * LQn + p) * 32 + (colg & 31)] = f2bf(v);
        }
      }
    }
}

// ---------------- sampling + softmax + weighted sum + OUT-PROJ, v7 ----------------
// v6 with phase-D fixed: (a) Wout fragments staged through wave-private LDS
// with coalesced global loads (re-using the dead tw/ti LDS region), no block
// barriers (wave-synchronous s_waitcnt); (b) sm padded to 272 ushorts/row
// (bank step 8/row -> 2-way max on fragment reads).
__global__ __launch_bounds__(256) void msda_sample7(
    const unsigned short* __restrict__ value16,  // [b][h][pix][32] bf16
    const float* __restrict__ logits,            // (M,288)
    const float* __restrict__ refp,              // (M,3,2) (y,x)
    const unsigned short* __restrict__ Wout_t,   // (256,256) bf16 N-major
    const float* __restrict__ bout,              // (256) fp32
    float* __restrict__ C) {                     // (M,256) fp32 out
  __shared__ __align__(16) unsigned char pool[18432];  // tw|ti, reused as Wout stage
  float (*tw)[96][4] = (float(*)[96][4])pool;                       // 12288 B
  unsigned short (*ti)[96][4] = (unsigned short(*)[96][4])(pool + 12288);  // 6144 B
  __shared__ float hmx[8][8], hrd[8][8];
  __shared__ float rfs[8][6];
  __shared__ unsigned short sm[8][272];     // padded: 544B row stride

  const int t = threadIdx.x;
  const int qbase = blockIdx.x * 8;

  if (t < 48) {
    int q = t / 6;
    if (qbase + q < MTOT) rfs[q][t - q * 6] = refp[(size_t)qbase * 6 + t];
  }
  if (t >= 64 && t < 128) {
    int tt = t - 64;
    int q = tt >> 3, h = tt & 7;
    int bq = qbase + q;
    if (bq < MTOT) {
      const float* lrow = logits + (size_t)bq * 288 + 192 + h * 12;
      float mx = -1e30f;
#pragma unroll
      for (int i = 0; i < 12; i++) mx = fmaxf(mx, lrow[i]);
      float den = 0.f;
#pragma unroll
      for (int i = 0; i < 12; i++) den += __expf(lrow[i] - mx);
      hmx[q][h] = mx;
      hrd[q][h] = 1.0f / den;
    }
  }
  __syncthreads();

  // Phase B: build tables, task id == (q, slot), conflict-free
  {
    const int Hs[3] = {92, 46, 23};
    const int Ss[3] = {0, 8464, 10580};
#pragma unroll
    for (int r = 0; r < 3; r++) {
      const int task = t + r * 256;
      const int q = task / 96, s = task - q * 96;   // s = slot = pl*8 + h
      const int bq = qbase + q;
      if (bq < MTOT) {
        const int h = s & 7, pl = s >> 3;
        const int l = pl >> 2;
        const int H = Hs[l], W = Hs[l], S = Ss[l];
        const int ob = h * 12 + pl;
        const float* lrow = logits + (size_t)bq * 288;
        const float aw = __expf(lrow[192 + ob] - hmx[q][h]) * hrd[q][h];
        const float offy = lrow[2 * ob], offx = lrow[2 * ob + 1];
        const float x = rfs[q][l * 2 + 1] * W + offx - 0.5f;
        const float y = rfs[q][l * 2 + 0] * H + offy - 0.5f;
        const float xf = floorf(x), yf = floorf(y);
        const int x0 = (int)xf, y0 = (int)yf;
        const float lx = x - xf, ly = y - yf;
        const bool xv0 = (x0 >= 0) & (x0 < W), xv1 = (x0 + 1 >= 0) & (x0 + 1 < W);
        const bool yv0 = (y0 >= 0) & (y0 < H), yv1 = (y0 + 1 >= 0) & (y0 + 1 < H);
        const int xc0 = min(max(x0, 0), W - 1), xc1 = min(max(x0 + 1, 0), W - 1);
        const int yc0 = min(max(y0, 0), H - 1), yc1 = min(max(y0 + 1, 0), H - 1);
        ti[q][s][0] = (unsigned short)(S + yc0 * W + xc0);
        ti[q][s][1] = (unsigned short)(S + yc0 * W + xc1);
        ti[q][s][2] = (unsigned short)(S + yc1 * W + xc0);
        ti[q][s][3] = (unsigned short)(S + yc1 * W + xc1);
        tw[q][s][0] = (yv0 & xv0) ? aw * (1.f - ly) * (1.f - lx) : 0.f;
        tw[q][s][1] = (yv0 & xv1) ? aw * (1.f - ly) * lx : 0.f;
        tw[q][s][2] = (yv1 & xv0) ? aw * ly * (1.f - lx) : 0.f;
        tw[q][s][3] = (yv1 & xv1) ? aw * ly * lx : 0.f;
      }
    }
  }
  __syncthreads();

  // Phase C: gather + weighted sum -> LDS sm
  {
    const int w = t >> 6, lane = t & 63;
    const int q = w * 2 + (lane >> 5);
    const int h = (lane >> 2) & 7, cg = lane & 3;
    const int bq = qbase + q;
    const int bqc = (bq < MTOT) ? bq : 0;
    const char* __restrict__ vb =
        (const char*)value16 + (size_t)(bqc / LQn) * ((size_t)LQn * 512);
    const unsigned laneoff = (unsigned)h * (LQn * 64u) + (unsigned)cg * 16u;

    float a0 = 0.f, a1 = 0.f, a2 = 0.f, a3 = 0.f;
    float a4 = 0.f, a5 = 0.f, a6 = 0.f, a7 = 0.f;
#pragma unroll
    for (int p = 0; p < 12; p++) {
      const int slot = p * 8 + h;
      const ushort4 tiv = *(const ushort4*)(&ti[q][slot][0]);
      const f32x4 wv = *(const f32x4*)(&tw[q][slot][0]);
#pragma unroll
      for (int k = 0; k < 4; k++) {
        const unsigned pix =
            (k == 0) ? tiv.x : (k == 1) ? tiv.y : (k == 2) ? tiv.z : tiv.w;
        const float wgt = wv[k];
        const uint4 u = *(const uint4*)(vb + ((pix << 6) + laneoff));
        a0 += wgt * __uint_as_float(u.x << 16);
        a1 += wgt * __uint_as_float(u.x & 0xffff0000u);
        a2 += wgt * __uint_as_float(u.y << 16);
        a3 += wgt * __uint_as_float(u.y & 0xffff0000u);
        a4 += wgt * __uint_as_float(u.z << 16);
        a5 += wgt * __uint_as_float(u.z & 0xffff0000u);
        a6 += wgt * __uint_as_float(u.w << 16);
        a7 += wgt * __uint_as_float(u.w & 0xffff0000u);
      }
    }
    uint4 o;
    o.x = (unsigned)f2bf(a0) | ((unsigned)f2bf(a1) << 16);
    o.y = (unsigned)f2bf(a2) | ((unsigned)f2bf(a3) << 16);
    o.z = (unsigned)f2bf(a4) | ((unsigned)f2bf(a5) << 16);
    o.w = (unsigned)f2bf(a6) | ((unsigned)f2bf(a7) << 16);
    *(uint4*)(&sm[q][h * 32 + cg * 8]) = o;  // LDS
  }
  __syncthreads();   // sm complete; tw/ti dead -> pool reusable

  // Phase D: out-proj mini-GEMM, wave w -> cols [w*64, w*64+64).
  // Wout staged per-kb through wave-private LDS (coalesced global loads,
  // wave-synchronous). A rows: sm[l16&7]; C rows 8..15 are dups, not stored.
  {
    const int w = t >> 6, lane = t & 63;
    const int quad = lane >> 4, l16 = lane & 15;
    unsigned short* ws = (unsigned short*)pool + (size_t)w * 2048;  // 4KB/wave
    const int ldrow = lane >> 2;        // 0..15
    const int ldk = (lane & 3) * 8;     // ushort offset: 0,8,16,24

    f32x4 acc[4];
#pragma unroll
    for (int j = 0; j < 4; j++) acc[j] = (f32x4){0.f, 0.f, 0.f, 0.f};

#pragma unroll
    for (int kb = 0; kb < 8; kb++) {
      // coalesced: 4 instr, each reads 16 rows x 64B full lines
      uint4 wv[4];
#pragma unroll
      for (int ii = 0; ii < 4; ii++) {
        const int col = w * 64 + ii * 16 + ldrow;
        wv[ii] = *(const uint4*)(Wout_t + (size_t)col * 256 + kb * 32 + ldk);
      }
#pragma unroll
      for (int ii = 0; ii < 4; ii++)
        *(uint4*)(ws + (ii * 16 + ldrow) * 32 + ldk) = wv[ii];
      asm volatile("s_waitcnt lgkmcnt(0)" ::: "memory");  // wave-sync LDS

      const short8 af = *(const short8*)(&sm[l16 & 7][kb * 32 + quad * 8]);
#pragma unroll
      for (int j = 0; j < 4; j++) {
        const short8 bfr = *(const short8*)(ws + (j * 16 + l16) * 32 + quad * 8);
        acc[j] = __builtin_amdgcn_mfma_f32_16x16x32_bf16(af, bfr, acc[j], 0, 0, 0);
      }
      asm volatile("s_waitcnt lgkmcnt(0)" ::: "memory");  // reads done before next overwrite
    }
#pragma unroll
    for (int j = 0; j < 4; j++) {
      const int col = w * 64 + j * 16 + l16;
      const float bs = bout[col];
#pragma unroll
      for (int r = 0; r < 4; r++) {
        const int rg = quad * 4 + r;     // MFMA tile row
        if (rg < 8) {
          const int gq = qbase + rg;
          if (gq < MTOT) C[(size_t)gq * 256 + col] = acc[j][r] + bs;
        }
      }
    }
  }
}

// ---------------- host launch ----------------
extern "C" void kernel_launch(void* const* d_in, const int* in_sizes, int n_in,
                              void* d_out, int out_size, void* d_ws, size_t ws_size,
                              hipStream_t stream) {
  const float* query      = (const float*)d_in[0];
  const float* refp       = (const float*)d_in[1];
  const float* value_flat = (const float*)d_in[2];
  const float* W_val      = (const float*)d_in[3];
  const float* b_val      = (const float*)d_in[4];
  const float* W_off      = (const float*)d_in[5];
  const float* b_off      = (const float*)d_in[6];
  const float* W_attn     = (const float*)d_in[7];
  const float* b_attn     = (const float*)d_in[8];
  const float* W_out      = (const float*)d_in[9];
  const float* b_out      = (const float*)d_in[10];

  char* w = (char*)d_ws;
  size_t o = 0;
  auto carve = [&](size_t bytes) -> void* {
    void* p = (void*)(w + o);
    o += (bytes + 255) & ~(size_t)255;
    return p;
  };
  unsigned short* Wval_t  = (unsigned short*)carve(256 * 256 * 2);
  unsigned short* Wcat_t  = (unsigned short*)carve(288 * 256 * 2);
  unsigned short* Wout_t  = (unsigned short*)carve(256 * 256 * 2);
  float*          bcat    = (float*)carve(288 * 4);
  unsigned short* value16 = (unsigned short*)carve((size_t)MTOT * 256 * 2);
  float*          logits  = (float*)carve((size_t)MTOT * 288 * 4);

  prep_weights2<<<256, 320, 0, stream>>>(W_val, W_off, W_attn, W_out, b_off, b_attn,
                                         Wval_t, Wcat_t, Wout_t, bcat);

  const int mg = (MTOT + 63) / 64;               // 348
  dim3 g12(mg, 9);                               // 4 value-proj tiles + 5 logits tiles
  gemm_fused12<<<g12, 256, 0, stream>>>(value_flat, query, Wval_t, Wcat_t,
                                        b_val, bcat, value16, logits);

  const int sgrid = (MTOT + 7) / 8;              // 2778
  msda_sample7<<<sgrid, 256, 0, stream>>>(value16, logits, refp,
                                          Wout_t, b_out, (float*)d_out);
}